// Round 5
// baseline (677.546 us; speedup 1.0000x reference)
//
#include <hip/hip_runtime.h>
#include <hip/hip_bf16.h>
#include <math.h>

#define CHANNELS 64
#define KK 25                   // 5x5 kernels
#define NBLK 26                 // 25 spline kernels + 1 root block
#define NCOL (NBLK * CHANNELS)  // 1664 columns of the fused GEMM
#define NTILES (NCOL / 16)      // 104 col-tiles of 16
#define ROWB (NCOL * 2)         // 3328 bytes per xk row

typedef __attribute__((ext_vector_type(8))) short bf16x8;
typedef __attribute__((ext_vector_type(4))) float f32x4;

// RNE float -> bf16 bits
__device__ __forceinline__ unsigned int f2bfu(float f) {
    unsigned int u = __float_as_uint(f);
    return (u + 0x7FFFu + ((u >> 16) & 1u)) >> 16;
}
__device__ __forceinline__ short f2bf(float f) { return (short)f2bfu(f); }
// unpack packed bf16 pair (u32) -> floats
__device__ __forceinline__ float blo(unsigned int u) { return __uint_as_float(u << 16); }
__device__ __forceinline__ float bhi(unsigned int u) { return __uint_as_float(u & 0xffff0000u); }

// ---------------- CSR build: histogram -> parallel scan -> scatter ----------------

__global__ __launch_bounds__(256) void zero_counts(unsigned int* __restrict__ c, int n) {
    int i = blockIdx.x * 256 + threadIdx.x;
    if (i < n) c[i] = 0u;
}

__global__ __launch_bounds__(256) void hist_dst(const int* __restrict__ ei,
                                                unsigned int* __restrict__ counts, int E) {
    int e = blockIdx.x * 256 + threadIdx.x;
    if (e < E) atomicAdd(&counts[ei[E + e]], 1u);
}

// A: per-block (1024 items) sums
__global__ __launch_bounds__(256) void scan_a(const unsigned int* __restrict__ counts,
                                              unsigned int* __restrict__ bsum, int N) {
    const int t = threadIdx.x;
    const int base = blockIdx.x * 1024 + t * 4;
    uint4 v = make_uint4(0, 0, 0, 0);
    if (base + 3 < N) v = *(const uint4*)(counts + base);
    else {
        if (base < N)     v.x = counts[base];
        if (base + 1 < N) v.y = counts[base + 1];
        if (base + 2 < N) v.z = counts[base + 2];
    }
    unsigned int s = v.x + v.y + v.z + v.w;
    for (int off = 32; off; off >>= 1) s += __shfl_down(s, off, 64);
    __shared__ unsigned int red[4];
    if ((t & 63) == 0) red[t >> 6] = s;
    __syncthreads();
    if (t == 0) bsum[blockIdx.x] = red[0] + red[1] + red[2] + red[3];
}

// B: single-wave exclusive scan of bsum[nb]
__global__ __launch_bounds__(64) void scan_b(unsigned int* __restrict__ bsum, int nb) {
    const int lane = threadIdx.x;
    unsigned int run = 0;
    for (int base = 0; base < nb; base += 64) {
        unsigned int v = (base + lane < nb) ? bsum[base + lane] : 0u;
        const unsigned int orig = v;
        for (int off = 1; off < 64; off <<= 1) {
            unsigned int u = __shfl_up(v, off, 64);
            if (lane >= off) v += u;
        }
        if (base + lane < nb) bsum[base + lane] = run + v - orig;
        run += __shfl(v, 63, 64);
    }
}

// C: per-block exclusive scan + block offset -> cursor (exclusive prefix)
__global__ __launch_bounds__(256) void scan_c(const unsigned int* __restrict__ counts,
                                              const unsigned int* __restrict__ bsum,
                                              unsigned int* __restrict__ cursor, int N) {
    const int t = threadIdx.x;
    const int base = blockIdx.x * 1024 + t * 4;
    uint4 v = make_uint4(0, 0, 0, 0);
    if (base + 3 < N) v = *(const uint4*)(counts + base);
    else {
        if (base < N)     v.x = counts[base];
        if (base + 1 < N) v.y = counts[base + 1];
        if (base + 2 < N) v.z = counts[base + 2];
    }
    __shared__ unsigned int ps[256];
    ps[t] = v.x + v.y + v.z + v.w;
    __syncthreads();
    for (int off = 1; off < 256; off <<= 1) {
        unsigned int u = (t >= off) ? ps[t - off] : 0u;
        __syncthreads();
        ps[t] += u;
        __syncthreads();
    }
    unsigned int ex = ((t > 0) ? ps[t - 1] : 0u) + bsum[blockIdx.x];
    if (base < N)     cursor[base]     = ex;
    if (base + 1 < N) cursor[base + 1] = ex + v.x;
    if (base + 2 < N) cursor[base + 2] = ex + v.x + v.y;
    if (base + 3 < N) cursor[base + 3] = ex + v.x + v.y + v.z;
}

// Per-edge record: {src, packed 4x5-bit k-indices, f0, f1} = 16 B.
__global__ __launch_bounds__(256) void scatter_edges(
    const int* __restrict__ ei, const float* __restrict__ ps,
    unsigned int* __restrict__ cursor, int4* __restrict__ sorted, int E)
{
    int e = blockIdx.x * 256 + threadIdx.x;
    if (e >= E) return;
    const int src = ei[e];
    const int dst = ei[E + e];
    const float v0 = ps[2 * e]     * 4.0f;
    const float v1 = ps[2 * e + 1] * 4.0f;
    const float fb0 = floorf(v0), fb1 = floorf(v1);
    const float f0 = v0 - fb0, f1 = v1 - fb1;
    const int b0 = max(min((int)fb0, 4), 0);
    const int b1 = max(min((int)fb1, 4), 0);
    const int c0 = min(b0 + 1, 4);
    const int c1 = min(b1 + 1, 4);
    const unsigned int pk = (unsigned)(b0 + 5 * b1)
                          | ((unsigned)(c0 + 5 * b1) << 5)
                          | ((unsigned)(b0 + 5 * c1) << 10)
                          | ((unsigned)(c0 + 5 * c1) << 15);
    const unsigned int pos = atomicAdd(&cursor[dst], 1u);
    sorted[pos] = make_int4(src, (int)pk, __float_as_int(f0), __float_as_int(f1));
}

// ---------------- fused xk GEMM (MFMA): 25 spline kernels + root block ----------------

// Repack [W | root] fp32 -> Wb bf16 fragment order (lane&15 = col-in-tile,
// k = q*32 + (lane>>4)*8 + j). Serves as the A-operand (M = columns).
__global__ __launch_bounds__(256) void prep_w(const float* __restrict__ W,
                                              const float* __restrict__ root,
                                              __hip_bfloat16* __restrict__ Wb) {
    int idx = blockIdx.x * 256 + threadIdx.x;   // 104*2*64*8 = 106496
    if (idx >= NTILES * 2 * 64 * 8) return;
    int j = idx & 7;
    int l = (idx >> 3) & 63;
    int q = (idx >> 9) & 1;
    int t = idx >> 10;
    int col  = t * 16 + (l & 15);
    int k    = q * 32 + (l >> 4) * 8 + j;
    int kk   = col >> 6;
    int o    = col & 63;
    float src = (kk < KK) ? W[kk * 4096 + k * 64 + o] : root[k * 64 + o];
    ((unsigned short*)Wb)[idx] = (unsigned short)f2bf(src);
}

// XK[n, c] = sum_i X[n,i] * B[i,c]; stored bf16.
// Operand-swapped MFMA (A = W cols, B = X rows) so D gives each lane 4
// CONSECUTIVE columns of one row -> single 8 B packed store per tile.
__global__ __launch_bounds__(256) void gemm_mfma(
    const float* __restrict__ X, const __hip_bfloat16* __restrict__ Wb,
    __hip_bfloat16* __restrict__ XK, int N)
{
    const int lane = threadIdx.x & 63;
    const int wv   = threadIdx.x >> 6;
    const int rb   = blockIdx.x * 64 + wv * 16;
    const int m    = lane & 15;
    const int quad = lane >> 4;

    // ---- X fragment (B operand): lane holds X[rb+m][k = q*32 + quad*8 + j] ----
    const int rowc = min(rb + m, N - 1);
    const float* __restrict__ xp = X + (size_t)rowc * CHANNELS + quad * 8;
    float af[16];
    *(float4*)(af)      = *(const float4*)(xp);
    *(float4*)(af + 4)  = *(const float4*)(xp + 4);
    *(float4*)(af + 8)  = *(const float4*)(xp + 32);
    *(float4*)(af + 12) = *(const float4*)(xp + 36);
    bf16x8 Xf0, Xf1;
#pragma unroll
    for (int j = 0; j < 8; ++j) { Xf0[j] = f2bf(af[j]); Xf1[j] = f2bf(af[8 + j]); }

    const bf16x8* __restrict__ wb = (const bf16x8*)Wb;
    // store: node = rb + m (row), cols t*16 + quad*4 .. +3 (packed 8 B)
    const int node = rb + m;
    const bool wr = node < N;
    char* __restrict__ outp = (char*)XK + (size_t)node * ROWB + quad * 8;

    bf16x8 W0 = wb[lane];
    bf16x8 W1 = wb[64 + lane];
    for (int t = 0; t < NTILES; ++t) {
        bf16x8 nW0 = W0, nW1 = W1;
        if (t + 1 < NTILES) {
            nW0 = wb[(t + 1) * 128 + lane];
            nW1 = wb[(t + 1) * 128 + 64 + lane];
        }
        f32x4 acc = {0.f, 0.f, 0.f, 0.f};
        acc = __builtin_amdgcn_mfma_f32_16x16x32_bf16(W0, Xf0, acc, 0, 0, 0);
        acc = __builtin_amdgcn_mfma_f32_16x16x32_bf16(W1, Xf1, acc, 0, 0, 0);
        if (wr) {
            uint2 p;
            p.x = f2bfu(acc[0]) | (f2bfu(acc[1]) << 16);
            p.y = f2bfu(acc[2]) | (f2bfu(acc[3]) << 16);
            *(uint2*)(outp + t * 32) = p;
        }
        W0 = nW0; W1 = nW1;
    }
}

// ------------- fused segment-max + root + bias (+relu): 8 edges / wave-iter -------------
// Wave per dst node. Lane = (group g = lane>>3, sub j = lane&7): handles channels
// 8j..8j+7 of edge i+g. dwordx4 (16 B) bf16 gathers; duplicates free under max.
__global__ __launch_bounds__(256) void agg_node(
    const int4* __restrict__ sorted, const unsigned int* __restrict__ cursor,
    const __hip_bfloat16* __restrict__ XK, const float* __restrict__ bias,
    float* __restrict__ out, int N, int do_relu)
{
    const int lane = threadIdx.x & 63;
    const int n = blockIdx.x * 4 + (threadIdx.x >> 6);
    if (n >= N) return;
    const int g = lane >> 3, j = lane & 7;
    const int beg = (n > 0) ? (int)cursor[n - 1] : 0;
    const int end = (int)cursor[n];

    float m0 = -INFINITY, m1 = -INFINITY, m2 = -INFINITY, m3 = -INFINITY;
    float m4 = -INFINITY, m5 = -INFINITY, m6 = -INFINITY, m7 = -INFINITY;
    if (beg < end) {
        int4 r = sorted[min(beg + g, end - 1)];
        for (int i = beg; i < end; i += 8) {
            int4 rn = r;
            if (i + 8 < end) rn = sorted[min(i + 8 + g, end - 1)];  // prefetch
            const unsigned int pk = (unsigned int)r.y;
            const float f0 = __int_as_float(r.z);
            const float f1 = __int_as_float(r.w);
            const char* __restrict__ base =
                (const char*)XK + (size_t)(unsigned)r.x * ROWB + (j << 4);
            const uint4 c0 = *(const uint4*)(base + ((pk & 31) << 7));
            const uint4 c1 = *(const uint4*)(base + (((pk >> 5) & 31) << 7));
            const uint4 c2 = *(const uint4*)(base + (((pk >> 10) & 31) << 7));
            const uint4 c3 = *(const uint4*)(base + (((pk >> 15) & 31) << 7));
            const float w00 = (1.f - f0) * (1.f - f1);
            const float w10 = f0 * (1.f - f1);
            const float w01 = (1.f - f0) * f1;
            const float w11 = f0 * f1;
            float v;
            v = fmaf(blo(c3.x), w11, fmaf(blo(c2.x), w01, fmaf(blo(c1.x), w10, blo(c0.x) * w00))); m0 = fmaxf(m0, v);
            v = fmaf(bhi(c3.x), w11, fmaf(bhi(c2.x), w01, fmaf(bhi(c1.x), w10, bhi(c0.x) * w00))); m1 = fmaxf(m1, v);
            v = fmaf(blo(c3.y), w11, fmaf(blo(c2.y), w01, fmaf(blo(c1.y), w10, blo(c0.y) * w00))); m2 = fmaxf(m2, v);
            v = fmaf(bhi(c3.y), w11, fmaf(bhi(c2.y), w01, fmaf(bhi(c1.y), w10, bhi(c0.y) * w00))); m3 = fmaxf(m3, v);
            v = fmaf(blo(c3.z), w11, fmaf(blo(c2.z), w01, fmaf(blo(c1.z), w10, blo(c0.z) * w00))); m4 = fmaxf(m4, v);
            v = fmaf(bhi(c3.z), w11, fmaf(bhi(c2.z), w01, fmaf(bhi(c1.z), w10, bhi(c0.z) * w00))); m5 = fmaxf(m5, v);
            v = fmaf(blo(c3.w), w11, fmaf(blo(c2.w), w01, fmaf(blo(c1.w), w10, blo(c0.w) * w00))); m6 = fmaxf(m6, v);
            v = fmaf(bhi(c3.w), w11, fmaf(bhi(c2.w), w01, fmaf(bhi(c1.w), w10, bhi(c0.w) * w00))); m7 = fmaxf(m7, v);
            r = rn;
        }
    }
    // combine the 8 groups (lane bits 3,4,5)
#pragma unroll
    for (int off = 8; off <= 32; off <<= 1) {
        m0 = fmaxf(m0, __shfl_xor(m0, off, 64));
        m1 = fmaxf(m1, __shfl_xor(m1, off, 64));
        m2 = fmaxf(m2, __shfl_xor(m2, off, 64));
        m3 = fmaxf(m3, __shfl_xor(m3, off, 64));
        m4 = fmaxf(m4, __shfl_xor(m4, off, 64));
        m5 = fmaxf(m5, __shfl_xor(m5, off, 64));
        m6 = fmaxf(m6, __shfl_xor(m6, off, 64));
        m7 = fmaxf(m7, __shfl_xor(m7, off, 64));
    }
    if (g == 0) {
        const float a0 = isfinite(m0) ? m0 : 0.f;
        const float a1 = isfinite(m1) ? m1 : 0.f;
        const float a2 = isfinite(m2) ? m2 : 0.f;
        const float a3 = isfinite(m3) ? m3 : 0.f;
        const float a4 = isfinite(m4) ? m4 : 0.f;
        const float a5 = isfinite(m5) ? m5 : 0.f;
        const float a6 = isfinite(m6) ? m6 : 0.f;
        const float a7 = isfinite(m7) ? m7 : 0.f;
        // root term = xk block 25 (x@root), bias, relu
        const uint4 rt = *(const uint4*)((const char*)XK + (size_t)(unsigned)n * ROWB
                                         + KK * 128 + (j << 4));
        const float4 bv0 = *(const float4*)(bias + 8 * j);
        const float4 bv1 = *(const float4*)(bias + 8 * j + 4);
        float r0 = a0 + blo(rt.x) + bv0.x;
        float r1 = a1 + bhi(rt.x) + bv0.y;
        float r2 = a2 + blo(rt.y) + bv0.z;
        float r3 = a3 + bhi(rt.y) + bv0.w;
        float r4 = a4 + blo(rt.z) + bv1.x;
        float r5 = a5 + bhi(rt.z) + bv1.y;
        float r6 = a6 + blo(rt.w) + bv1.z;
        float r7 = a7 + bhi(rt.w) + bv1.w;
        if (do_relu) {
            r0 = fmaxf(r0, 0.f); r1 = fmaxf(r1, 0.f);
            r2 = fmaxf(r2, 0.f); r3 = fmaxf(r3, 0.f);
            r4 = fmaxf(r4, 0.f); r5 = fmaxf(r5, 0.f);
            r6 = fmaxf(r6, 0.f); r7 = fmaxf(r7, 0.f);
        }
        float* __restrict__ op = out + (size_t)n * CHANNELS + 8 * j;
        *(float4*)(op)     = make_float4(r0, r1, r2, r3);
        *(float4*)(op + 4) = make_float4(r4, r5, r6, r7);
    }
}

extern "C" void kernel_launch(void* const* d_in, const int* in_sizes, int n_in,
                              void* d_out, int out_size, void* d_ws, size_t ws_size,
                              hipStream_t stream) {
    const float* x     = (const float*)d_in[0];
    const int*   ei    = (const int*)d_in[1];
    const float* ps    = (const float*)d_in[2];
    const float* W1    = (const float*)d_in[3];
    const float* root1 = (const float*)d_in[4];
    const float* bias1 = (const float*)d_in[5];
    const float* W2    = (const float*)d_in[6];
    const float* root2 = (const float*)d_in[7];
    const float* bias2 = (const float*)d_in[8];
    float* out = (float*)d_out;

    const int N = in_sizes[0] / CHANNELS;
    const int E = in_sizes[1] / 2;

    // ---- workspace layout (~205 MB) ----
    char* ws = (char*)d_ws;
    __hip_bfloat16* xk = (__hip_bfloat16*)ws;                       // N*1664*2 = 166.4 MB
    size_t off = (size_t)N * NCOL * sizeof(__hip_bfloat16);
    float* h = (float*)(ws + off);                                  // N*64*4 = 12.8 MB
    off += (size_t)N * CHANNELS * sizeof(float);
    int4* sorted = (int4*)(ws + off);                               // E*16 = 25.6 MB
    off += (size_t)E * sizeof(int4);
    const size_t wb_bytes = (size_t)NTILES * 2 * 64 * 8 * 2;        // 212992
    unsigned int* counts = (unsigned int*)(ws + off);               // max(N*4, wb)
    __hip_bfloat16* Wb = (__hip_bfloat16*)counts;                   // aliases counts (dead after scan)
    off += ((size_t)N * 4 > wb_bytes ? (size_t)N * 4 : wb_bytes);
    unsigned int* cursor = (unsigned int*)(ws + off);               // N*4
    off += (size_t)N * 4;
    unsigned int* bsum = (unsigned int*)(ws + off);                 // ≤4 KB

    const int prep_blocks = (NTILES * 2 * 64 * 8 + 255) / 256;
    const int gemm_blocks = (N + 63) / 64;
    const int node_blocks = (N + 3) / 4;
    const int edgeT_blocks = (E + 255) / 256;
    const int nT_blocks = (N + 255) / 256;
    const int scan_blocks = (N + 1023) / 1024;

    // ---- CSR build (once; shared by both layers) ----
    zero_counts<<<nT_blocks, 256, 0, stream>>>(counts, N);
    hist_dst<<<edgeT_blocks, 256, 0, stream>>>(ei, counts, E);
    scan_a<<<scan_blocks, 256, 0, stream>>>(counts, bsum, N);
    scan_b<<<1, 64, 0, stream>>>(bsum, scan_blocks);
    scan_c<<<scan_blocks, 256, 0, stream>>>(counts, bsum, cursor, N);
    scatter_edges<<<edgeT_blocks, 256, 0, stream>>>(ei, ps, cursor, sorted, E);

    // ---- layer 1: h = relu(spline_conv(x, W1, root1, bias1)) ----
    prep_w<<<prep_blocks, 256, 0, stream>>>(W1, root1, Wb);   // clobbers counts (dead)
    gemm_mfma<<<gemm_blocks, 256, 0, stream>>>(x, Wb, xk, N);
    agg_node<<<node_blocks, 256, 0, stream>>>(sorted, cursor, xk, bias1, h, N, 1);

    // ---- layer 2: out = spline_conv(h, W2, root2, bias2) ----
    prep_w<<<prep_blocks, 256, 0, stream>>>(W2, root2, Wb);
    gemm_mfma<<<gemm_blocks, 256, 0, stream>>>(h, Wb, xk, N);
    agg_node<<<node_blocks, 256, 0, stream>>>(sorted, cursor, xk, bias2, out, N, 0);
}

// Round 6
// 610.849 us; speedup vs baseline: 1.1092x; 1.1092x over previous
//
#include <hip/hip_runtime.h>
#include <hip/hip_bf16.h>
#include <math.h>

#define CHANNELS 64
#define KK 25                   // 5x5 kernels
#define NBLK 26                 // 25 spline kernels + 1 root block
#define NCOL (NBLK * CHANNELS)  // 1664 columns of the fused GEMM
#define NTILES (NCOL / 16)      // 104 col-tiles of 16
#define ROWB (NCOL * 2)         // 3328 bytes per xk row

typedef __attribute__((ext_vector_type(8))) short bf16x8;
typedef __attribute__((ext_vector_type(4))) float f32x4;

// RNE float -> bf16 bits
__device__ __forceinline__ unsigned int f2bfu(float f) {
    unsigned int u = __float_as_uint(f);
    return (u + 0x7FFFu + ((u >> 16) & 1u)) >> 16;
}
__device__ __forceinline__ short f2bf(float f) { return (short)f2bfu(f); }
// unpack packed bf16 pair (u32) -> floats
__device__ __forceinline__ float blo(unsigned int u) { return __uint_as_float(u << 16); }
__device__ __forceinline__ float bhi(unsigned int u) { return __uint_as_float(u & 0xffff0000u); }

// ---------------- CSR build: histogram -> parallel scan -> scatter ----------------

__global__ __launch_bounds__(256) void zero_counts(unsigned int* __restrict__ c, int n) {
    int i = blockIdx.x * 256 + threadIdx.x;
    if (i < n) c[i] = 0u;
}

__global__ __launch_bounds__(256) void hist_dst(const int* __restrict__ ei,
                                                unsigned int* __restrict__ counts, int E) {
    int e = blockIdx.x * 256 + threadIdx.x;
    if (e < E) atomicAdd(&counts[ei[E + e]], 1u);
}

// A: per-block (1024 items) sums
__global__ __launch_bounds__(256) void scan_a(const unsigned int* __restrict__ counts,
                                              unsigned int* __restrict__ bsum, int N) {
    const int t = threadIdx.x;
    const int base = blockIdx.x * 1024 + t * 4;
    uint4 v = make_uint4(0, 0, 0, 0);
    if (base + 3 < N) v = *(const uint4*)(counts + base);
    else {
        if (base < N)     v.x = counts[base];
        if (base + 1 < N) v.y = counts[base + 1];
        if (base + 2 < N) v.z = counts[base + 2];
    }
    unsigned int s = v.x + v.y + v.z + v.w;
    for (int off = 32; off; off >>= 1) s += __shfl_down(s, off, 64);
    __shared__ unsigned int red[4];
    if ((t & 63) == 0) red[t >> 6] = s;
    __syncthreads();
    if (t == 0) bsum[blockIdx.x] = red[0] + red[1] + red[2] + red[3];
}

// B: single-wave exclusive scan of bsum[nb]
__global__ __launch_bounds__(64) void scan_b(unsigned int* __restrict__ bsum, int nb) {
    const int lane = threadIdx.x;
    unsigned int run = 0;
    for (int base = 0; base < nb; base += 64) {
        unsigned int v = (base + lane < nb) ? bsum[base + lane] : 0u;
        const unsigned int orig = v;
        for (int off = 1; off < 64; off <<= 1) {
            unsigned int u = __shfl_up(v, off, 64);
            if (lane >= off) v += u;
        }
        if (base + lane < nb) bsum[base + lane] = run + v - orig;
        run += __shfl(v, 63, 64);
    }
}

// C: per-block exclusive scan + block offset -> cursor (exclusive prefix)
__global__ __launch_bounds__(256) void scan_c(const unsigned int* __restrict__ counts,
                                              const unsigned int* __restrict__ bsum,
                                              unsigned int* __restrict__ cursor, int N) {
    const int t = threadIdx.x;
    const int base = blockIdx.x * 1024 + t * 4;
    uint4 v = make_uint4(0, 0, 0, 0);
    if (base + 3 < N) v = *(const uint4*)(counts + base);
    else {
        if (base < N)     v.x = counts[base];
        if (base + 1 < N) v.y = counts[base + 1];
        if (base + 2 < N) v.z = counts[base + 2];
    }
    __shared__ unsigned int ps[256];
    ps[t] = v.x + v.y + v.z + v.w;
    __syncthreads();
    for (int off = 1; off < 256; off <<= 1) {
        unsigned int u = (t >= off) ? ps[t - off] : 0u;
        __syncthreads();
        ps[t] += u;
        __syncthreads();
    }
    unsigned int ex = ((t > 0) ? ps[t - 1] : 0u) + bsum[blockIdx.x];
    if (base < N)     cursor[base]     = ex;
    if (base + 1 < N) cursor[base + 1] = ex + v.x;
    if (base + 2 < N) cursor[base + 2] = ex + v.x + v.y;
    if (base + 3 < N) cursor[base + 3] = ex + v.x + v.y + v.z;
}

// Per-edge record: {src, packed 4x5-bit k-indices, f0, f1} = 16 B.
__global__ __launch_bounds__(256) void scatter_edges(
    const int* __restrict__ ei, const float* __restrict__ ps,
    unsigned int* __restrict__ cursor, int4* __restrict__ sorted, int E)
{
    int e = blockIdx.x * 256 + threadIdx.x;
    if (e >= E) return;
    const int src = ei[e];
    const int dst = ei[E + e];
    const float v0 = ps[2 * e]     * 4.0f;
    const float v1 = ps[2 * e + 1] * 4.0f;
    const float fb0 = floorf(v0), fb1 = floorf(v1);
    const float f0 = v0 - fb0, f1 = v1 - fb1;
    const int b0 = max(min((int)fb0, 4), 0);
    const int b1 = max(min((int)fb1, 4), 0);
    const int c0 = min(b0 + 1, 4);
    const int c1 = min(b1 + 1, 4);
    const unsigned int pk = (unsigned)(b0 + 5 * b1)
                          | ((unsigned)(c0 + 5 * b1) << 5)
                          | ((unsigned)(b0 + 5 * c1) << 10)
                          | ((unsigned)(c0 + 5 * c1) << 15);
    const unsigned int pos = atomicAdd(&cursor[dst], 1u);
    sorted[pos] = make_int4(src, (int)pk, __float_as_int(f0), __float_as_int(f1));
}

// ---------------- fused xk GEMM (MFMA): 25 spline kernels + root block ----------------
// (R4-proven form: A = X rows, B = W cols, 4 predicated 2 B stores per tile)

// Repack [W | root] fp32 -> Wb bf16 in B-fragment order.
__global__ __launch_bounds__(256) void prep_w(const float* __restrict__ W,
                                              const float* __restrict__ root,
                                              __hip_bfloat16* __restrict__ Wb) {
    int idx = blockIdx.x * 256 + threadIdx.x;   // 104*2*64*8 = 106496
    if (idx >= NTILES * 2 * 64 * 8) return;
    int j = idx & 7;
    int l = (idx >> 3) & 63;
    int q = (idx >> 9) & 1;
    int t = idx >> 10;
    int col  = t * 16 + (l & 15);
    int k    = q * 32 + (l >> 4) * 8 + j;
    int kk   = col >> 6;
    int o    = col & 63;
    float src = (kk < KK) ? W[kk * 4096 + k * 64 + o] : root[k * 64 + o];
    ((unsigned short*)Wb)[idx] = (unsigned short)f2bf(src);
}

// XK[n, c] = sum_i X[n,i] * B[i,c]; stored bf16. Wave owns 16 rows x all 104 tiles.
__global__ __launch_bounds__(256) void gemm_mfma(
    const float* __restrict__ X, const __hip_bfloat16* __restrict__ Wb,
    __hip_bfloat16* __restrict__ XK, int N)
{
    const int lane = threadIdx.x & 63;
    const int wv   = threadIdx.x >> 6;
    const int rb   = blockIdx.x * 64 + wv * 16;
    const int m    = lane & 15;
    const int quad = lane >> 4;

    const int rowc = min(rb + m, N - 1);
    const float* __restrict__ xp = X + (size_t)rowc * CHANNELS + quad * 8;
    float af[16];
    *(float4*)(af)      = *(const float4*)(xp);
    *(float4*)(af + 4)  = *(const float4*)(xp + 4);
    *(float4*)(af + 8)  = *(const float4*)(xp + 32);
    *(float4*)(af + 12) = *(const float4*)(xp + 36);
    bf16x8 A0, A1;
#pragma unroll
    for (int j = 0; j < 8; ++j) { A0[j] = f2bf(af[j]); A1[j] = f2bf(af[8 + j]); }

    const bf16x8* __restrict__ wb = (const bf16x8*)Wb;
    const int r0 = rb + quad * 4;
    __hip_bfloat16* __restrict__ outp = XK + (size_t)r0 * NCOL + m;
    const int rmax = N - r0;

    bf16x8 B0 = wb[lane];
    bf16x8 B1 = wb[64 + lane];
    for (int t = 0; t < NTILES; ++t) {
        bf16x8 nB0 = B0, nB1 = B1;
        if (t + 1 < NTILES) {
            nB0 = wb[(t + 1) * 128 + lane];
            nB1 = wb[(t + 1) * 128 + 64 + lane];
        }
        f32x4 acc = {0.f, 0.f, 0.f, 0.f};
        acc = __builtin_amdgcn_mfma_f32_16x16x32_bf16(A0, B0, acc, 0, 0, 0);
        acc = __builtin_amdgcn_mfma_f32_16x16x32_bf16(A1, B1, acc, 0, 0, 0);
#pragma unroll
        for (int i = 0; i < 4; ++i) {
            if (i < rmax)
                outp[(size_t)i * NCOL + t * 16] = __float2bfloat16(acc[i]);
        }
        B0 = nB0; B1 = nB1;
    }
}

// ------------- fused segment-max + root + bias (+relu): 4 edges / wave-iter -------------
// R4 structure (quarter q = lane>>4 handles edge i+q, sublane j = lane&15 handles
// channels 4j..4j+3, 8 B gathers) + 2-deep software pipeline: corner loads for
// iteration i+4 are issued before consuming iteration i's (records prefetched 2 ahead).
__global__ __launch_bounds__(256) void agg_node(
    const int4* __restrict__ sorted, const unsigned int* __restrict__ cursor,
    const __hip_bfloat16* __restrict__ XK, const float* __restrict__ bias,
    float* __restrict__ out, int N, int do_relu)
{
    const int lane = threadIdx.x & 63;
    const int n = blockIdx.x * 4 + (threadIdx.x >> 6);
    if (n >= N) return;
    const int q = lane >> 4, j = lane & 15;
    const int beg = (n > 0) ? (int)cursor[n - 1] : 0;
    const int end = (int)cursor[n];

    float m0 = -INFINITY, m1 = -INFINITY, m2 = -INFINITY, m3 = -INFINITY;
    if (beg < end) {
        const int last = end - 1;
        // pipeline prologue: records for iter 0 and iter 1, corners for iter 0
        int4 rA = sorted[min(beg + q, last)];
        int4 rB = sorted[min(beg + 4 + q, last)];
        const char* baseA = (const char*)XK + (size_t)(unsigned)rA.x * ROWB + (j << 3);
        uint2 g0 = *(const uint2*)(baseA + (((unsigned)rA.y & 31) << 7));
        uint2 g1 = *(const uint2*)(baseA + ((((unsigned)rA.y >> 5) & 31) << 7));
        uint2 g2 = *(const uint2*)(baseA + ((((unsigned)rA.y >> 10) & 31) << 7));
        uint2 g3 = *(const uint2*)(baseA + ((((unsigned)rA.y >> 15) & 31) << 7));
        for (int i = beg; i < end; i += 4) {
            // prefetch record for iter+2
            int4 rC = sorted[min(i + 8 + q, last)];
            // issue corner loads for iter+1 (from rB)
            const char* baseB = (const char*)XK + (size_t)(unsigned)rB.x * ROWB + (j << 3);
            uint2 h0 = *(const uint2*)(baseB + (((unsigned)rB.y & 31) << 7));
            uint2 h1 = *(const uint2*)(baseB + ((((unsigned)rB.y >> 5) & 31) << 7));
            uint2 h2 = *(const uint2*)(baseB + ((((unsigned)rB.y >> 10) & 31) << 7));
            uint2 h3 = *(const uint2*)(baseB + ((((unsigned)rB.y >> 15) & 31) << 7));
            // consume iter's corners (g*, weights from rA)
            const float f0 = __int_as_float(rA.z);
            const float f1 = __int_as_float(rA.w);
            const float w00 = (1.f - f0) * (1.f - f1);
            const float w10 = f0 * (1.f - f1);
            const float w01 = (1.f - f0) * f1;
            const float w11 = f0 * f1;
            float v0 = fmaf(blo(g3.x), w11, fmaf(blo(g2.x), w01, fmaf(blo(g1.x), w10, blo(g0.x) * w00)));
            float v1 = fmaf(bhi(g3.x), w11, fmaf(bhi(g2.x), w01, fmaf(bhi(g1.x), w10, bhi(g0.x) * w00)));
            float v2 = fmaf(blo(g3.y), w11, fmaf(blo(g2.y), w01, fmaf(blo(g1.y), w10, blo(g0.y) * w00)));
            float v3 = fmaf(bhi(g3.y), w11, fmaf(bhi(g2.y), w01, fmaf(bhi(g1.y), w10, bhi(g0.y) * w00)));
            m0 = fmaxf(m0, v0); m1 = fmaxf(m1, v1);
            m2 = fmaxf(m2, v2); m3 = fmaxf(m3, v3);
            // rotate pipeline
            rA = rB; rB = rC;
            g0 = h0; g1 = h1; g2 = h2; g3 = h3;
        }
    }
    // combine the 4 quarters (each saw a different edge subset)
    m0 = fmaxf(m0, __shfl_xor(m0, 16, 64)); m0 = fmaxf(m0, __shfl_xor(m0, 32, 64));
    m1 = fmaxf(m1, __shfl_xor(m1, 16, 64)); m1 = fmaxf(m1, __shfl_xor(m1, 32, 64));
    m2 = fmaxf(m2, __shfl_xor(m2, 16, 64)); m2 = fmaxf(m2, __shfl_xor(m2, 32, 64));
    m3 = fmaxf(m3, __shfl_xor(m3, 16, 64)); m3 = fmaxf(m3, __shfl_xor(m3, 32, 64));
    const float a0 = isfinite(m0) ? m0 : 0.f;
    const float a1 = isfinite(m1) ? m1 : 0.f;
    const float a2 = isfinite(m2) ? m2 : 0.f;
    const float a3 = isfinite(m3) ? m3 : 0.f;

    // root term = xk block 25 (x@root), bias, relu
    const uint2 rt = *(const uint2*)((const char*)XK + (size_t)(unsigned)n * ROWB
                                     + KK * 128 + (j << 3));
    const float4 bv = *(const float4*)(bias + 4 * j);
    float r0 = a0 + blo(rt.x) + bv.x;
    float r1 = a1 + bhi(rt.x) + bv.y;
    float r2 = a2 + blo(rt.y) + bv.z;
    float r3 = a3 + bhi(rt.y) + bv.w;
    if (do_relu) {
        r0 = fmaxf(r0, 0.f); r1 = fmaxf(r1, 0.f);
        r2 = fmaxf(r2, 0.f); r3 = fmaxf(r3, 0.f);
    }
    if (q == 0)
        *(float4*)(out + (size_t)n * CHANNELS + 4 * j) = make_float4(r0, r1, r2, r3);
}

extern "C" void kernel_launch(void* const* d_in, const int* in_sizes, int n_in,
                              void* d_out, int out_size, void* d_ws, size_t ws_size,
                              hipStream_t stream) {
    const float* x     = (const float*)d_in[0];
    const int*   ei    = (const int*)d_in[1];
    const float* ps    = (const float*)d_in[2];
    const float* W1    = (const float*)d_in[3];
    const float* root1 = (const float*)d_in[4];
    const float* bias1 = (const float*)d_in[5];
    const float* W2    = (const float*)d_in[6];
    const float* root2 = (const float*)d_in[7];
    const float* bias2 = (const float*)d_in[8];
    float* out = (float*)d_out;

    const int N = in_sizes[0] / CHANNELS;
    const int E = in_sizes[1] / 2;

    // ---- workspace layout (~205 MB) ----
    char* ws = (char*)d_ws;
    __hip_bfloat16* xk = (__hip_bfloat16*)ws;                       // N*1664*2 = 166.4 MB
    size_t off = (size_t)N * NCOL * sizeof(__hip_bfloat16);
    float* h = (float*)(ws + off);                                  // N*64*4 = 12.8 MB
    off += (size_t)N * CHANNELS * sizeof(float);
    int4* sorted = (int4*)(ws + off);                               // E*16 = 25.6 MB
    off += (size_t)E * sizeof(int4);
    const size_t wb_bytes = (size_t)NTILES * 2 * 64 * 8 * 2;        // 212992
    unsigned int* counts = (unsigned int*)(ws + off);               // max(N*4, wb)
    __hip_bfloat16* Wb = (__hip_bfloat16*)counts;                   // aliases counts (dead after scan)
    off += ((size_t)N * 4 > wb_bytes ? (size_t)N * 4 : wb_bytes);
    unsigned int* cursor = (unsigned int*)(ws + off);               // N*4
    off += (size_t)N * 4;
    unsigned int* bsum = (unsigned int*)(ws + off);                 // ≤4 KB

    const int prep_blocks = (NTILES * 2 * 64 * 8 + 255) / 256;
    const int gemm_blocks = (N + 63) / 64;
    const int node_blocks = (N + 3) / 4;
    const int edgeT_blocks = (E + 255) / 256;
    const int nT_blocks = (N + 255) / 256;
    const int scan_blocks = (N + 1023) / 1024;

    // ---- CSR build (once; shared by both layers) ----
    zero_counts<<<nT_blocks, 256, 0, stream>>>(counts, N);
    hist_dst<<<edgeT_blocks, 256, 0, stream>>>(ei, counts, E);
    scan_a<<<scan_blocks, 256, 0, stream>>>(counts, bsum, N);
    scan_b<<<1, 64, 0, stream>>>(bsum, scan_blocks);
    scan_c<<<scan_blocks, 256, 0, stream>>>(counts, bsum, cursor, N);
    scatter_edges<<<edgeT_blocks, 256, 0, stream>>>(ei, ps, cursor, sorted, E);

    // ---- layer 1: h = relu(spline_conv(x, W1, root1, bias1)) ----
    prep_w<<<prep_blocks, 256, 0, stream>>>(W1, root1, Wb);   // clobbers counts (dead)
    gemm_mfma<<<gemm_blocks, 256, 0, stream>>>(x, Wb, xk, N);
    agg_node<<<node_blocks, 256, 0, stream>>>(sorted, cursor, xk, bias1, h, N, 1);

    // ---- layer 2: out = spline_conv(h, W2, root2, bias2) ----
    prep_w<<<prep_blocks, 256, 0, stream>>>(W2, root2, Wb);
    gemm_mfma<<<gemm_blocks, 256, 0, stream>>>(h, Wb, xk, N);
    agg_node<<<node_blocks, 256, 0, stream>>>(sorted, cursor, xk, bias2, out, N, 0);
}

// Round 7
// 596.487 us; speedup vs baseline: 1.1359x; 1.0241x over previous
//
#include <hip/hip_runtime.h>
#include <hip/hip_bf16.h>
#include <math.h>

#define CHANNELS 64
#define KK 25                   // 5x5 kernels
#define NBLK 26                 // 25 spline kernels + 1 root block
#define NCOL (NBLK * CHANNELS)  // 1664 columns of the fused GEMM
#define NTILES (NCOL / 16)      // 104 col-tiles of 16
#define ROWB (NCOL * 2)         // 3328 bytes per xk row

typedef __attribute__((ext_vector_type(8))) short bf16x8;
typedef __attribute__((ext_vector_type(4))) float f32x4;

// RNE float -> bf16 bits
__device__ __forceinline__ unsigned int f2bfu(float f) {
    unsigned int u = __float_as_uint(f);
    return (u + 0x7FFFu + ((u >> 16) & 1u)) >> 16;
}
__device__ __forceinline__ short f2bf(float f) { return (short)f2bfu(f); }
// unpack packed bf16 pair (u32) -> floats
__device__ __forceinline__ float blo(unsigned int u) { return __uint_as_float(u << 16); }
__device__ __forceinline__ float bhi(unsigned int u) { return __uint_as_float(u & 0xffff0000u); }

// ---------------- CSR build: histogram -> parallel scan -> scatter ----------------

__global__ __launch_bounds__(256) void zero_counts(unsigned int* __restrict__ c, int n) {
    int i = blockIdx.x * 256 + threadIdx.x;
    if (i < n) c[i] = 0u;
}

__global__ __launch_bounds__(256) void hist_dst(const int* __restrict__ ei,
                                                unsigned int* __restrict__ counts, int E) {
    int e = blockIdx.x * 256 + threadIdx.x;
    if (e < E) atomicAdd(&counts[ei[E + e]], 1u);
}

// A: per-block (1024 items) sums
__global__ __launch_bounds__(256) void scan_a(const unsigned int* __restrict__ counts,
                                              unsigned int* __restrict__ bsum, int N) {
    const int t = threadIdx.x;
    const int base = blockIdx.x * 1024 + t * 4;
    uint4 v = make_uint4(0, 0, 0, 0);
    if (base + 3 < N) v = *(const uint4*)(counts + base);
    else {
        if (base < N)     v.x = counts[base];
        if (base + 1 < N) v.y = counts[base + 1];
        if (base + 2 < N) v.z = counts[base + 2];
    }
    unsigned int s = v.x + v.y + v.z + v.w;
    for (int off = 32; off; off >>= 1) s += __shfl_down(s, off, 64);
    __shared__ unsigned int red[4];
    if ((t & 63) == 0) red[t >> 6] = s;
    __syncthreads();
    if (t == 0) bsum[blockIdx.x] = red[0] + red[1] + red[2] + red[3];
}

// B: single-wave exclusive scan of bsum[nb]
__global__ __launch_bounds__(64) void scan_b(unsigned int* __restrict__ bsum, int nb) {
    const int lane = threadIdx.x;
    unsigned int run = 0;
    for (int base = 0; base < nb; base += 64) {
        unsigned int v = (base + lane < nb) ? bsum[base + lane] : 0u;
        const unsigned int orig = v;
        for (int off = 1; off < 64; off <<= 1) {
            unsigned int u = __shfl_up(v, off, 64);
            if (lane >= off) v += u;
        }
        if (base + lane < nb) bsum[base + lane] = run + v - orig;
        run += __shfl(v, 63, 64);
    }
}

// C: per-block exclusive scan + block offset -> cursor (exclusive prefix)
__global__ __launch_bounds__(256) void scan_c(const unsigned int* __restrict__ counts,
                                              const unsigned int* __restrict__ bsum,
                                              unsigned int* __restrict__ cursor, int N) {
    const int t = threadIdx.x;
    const int base = blockIdx.x * 1024 + t * 4;
    uint4 v = make_uint4(0, 0, 0, 0);
    if (base + 3 < N) v = *(const uint4*)(counts + base);
    else {
        if (base < N)     v.x = counts[base];
        if (base + 1 < N) v.y = counts[base + 1];
        if (base + 2 < N) v.z = counts[base + 2];
    }
    __shared__ unsigned int ps[256];
    ps[t] = v.x + v.y + v.z + v.w;
    __syncthreads();
    for (int off = 1; off < 256; off <<= 1) {
        unsigned int u = (t >= off) ? ps[t - off] : 0u;
        __syncthreads();
        ps[t] += u;
        __syncthreads();
    }
    unsigned int ex = ((t > 0) ? ps[t - 1] : 0u) + bsum[blockIdx.x];
    if (base < N)     cursor[base]     = ex;
    if (base + 1 < N) cursor[base + 1] = ex + v.x;
    if (base + 2 < N) cursor[base + 2] = ex + v.x + v.y;
    if (base + 3 < N) cursor[base + 3] = ex + v.x + v.y + v.z;
}

// ---------------- fused xk GEMM (MFMA) + edge scatter (hetero grid) ----------------

// Repack [W | root] fp32 -> Wb bf16 in B-fragment order.
__global__ __launch_bounds__(256) void prep_w(const float* __restrict__ W,
                                              const float* __restrict__ root,
                                              __hip_bfloat16* __restrict__ Wb) {
    int idx = blockIdx.x * 256 + threadIdx.x;   // 104*2*64*8 = 106496
    if (idx >= NTILES * 2 * 64 * 8) return;
    int j = idx & 7;
    int l = (idx >> 3) & 63;
    int q = (idx >> 9) & 1;
    int t = idx >> 10;
    int col  = t * 16 + (l & 15);
    int k    = q * 32 + (l >> 4) * 8 + j;
    int kk   = col >> 6;
    int o    = col & 63;
    float src = (kk < KK) ? W[kk * 4096 + k * 64 + o] : root[k * 64 + o];
    ((unsigned short*)Wb)[idx] = (unsigned short)f2bf(src);
}

// Heterogeneous grid: blocks [0, gemm_blocks) compute XK = X @ [W|root] (MFMA,
// R4-proven form); blocks [gemm_blocks, ...) scatter edge records into CSR order.
// The scatter path is pure memory latency (1% VALU) and backfills SIMD slots the
// gemm waves leave idle — hides ~127 us of otherwise fully-exposed scatter.
// Pass n_edge_blocks = 0 to run gemm only (layer 2).
__global__ __launch_bounds__(256) void gemm_scatter(
    const float* __restrict__ X, const __hip_bfloat16* __restrict__ Wb,
    __hip_bfloat16* __restrict__ XK, int N, int gemm_blocks,
    const int* __restrict__ ei, const float* __restrict__ ps,
    unsigned int* __restrict__ cursor, int4* __restrict__ sorted, int E)
{
    if ((int)blockIdx.x >= gemm_blocks) {
        // ---- scatter path ----
        int e = ((int)blockIdx.x - gemm_blocks) * 256 + threadIdx.x;
        if (e >= E) return;
        const int src = ei[e];
        const int dst = ei[E + e];
        const float v0 = ps[2 * e]     * 4.0f;
        const float v1 = ps[2 * e + 1] * 4.0f;
        const float fb0 = floorf(v0), fb1 = floorf(v1);
        const float f0 = v0 - fb0, f1 = v1 - fb1;
        const int b0 = max(min((int)fb0, 4), 0);
        const int b1 = max(min((int)fb1, 4), 0);
        const int c0 = min(b0 + 1, 4);
        const int c1 = min(b1 + 1, 4);
        const unsigned int pk = (unsigned)(b0 + 5 * b1)
                              | ((unsigned)(c0 + 5 * b1) << 5)
                              | ((unsigned)(b0 + 5 * c1) << 10)
                              | ((unsigned)(c0 + 5 * c1) << 15);
        const unsigned int pos = atomicAdd(&cursor[dst], 1u);
        sorted[pos] = make_int4(src, (int)pk, __float_as_int(f0), __float_as_int(f1));
        return;
    }
    // ---- gemm path ----
    const int lane = threadIdx.x & 63;
    const int wv   = threadIdx.x >> 6;
    const int rb   = blockIdx.x * 64 + wv * 16;
    const int m    = lane & 15;
    const int quad = lane >> 4;

    const int rowc = min(rb + m, N - 1);
    const float* __restrict__ xp = X + (size_t)rowc * CHANNELS + quad * 8;
    float af[16];
    *(float4*)(af)      = *(const float4*)(xp);
    *(float4*)(af + 4)  = *(const float4*)(xp + 4);
    *(float4*)(af + 8)  = *(const float4*)(xp + 32);
    *(float4*)(af + 12) = *(const float4*)(xp + 36);
    bf16x8 A0, A1;
#pragma unroll
    for (int j = 0; j < 8; ++j) { A0[j] = f2bf(af[j]); A1[j] = f2bf(af[8 + j]); }

    const bf16x8* __restrict__ wb = (const bf16x8*)Wb;
    const int r0 = rb + quad * 4;
    __hip_bfloat16* __restrict__ outp = XK + (size_t)r0 * NCOL + m;
    const int rmax = N - r0;

    bf16x8 B0 = wb[lane];
    bf16x8 B1 = wb[64 + lane];
    for (int t = 0; t < NTILES; ++t) {
        bf16x8 nB0 = B0, nB1 = B1;
        if (t + 1 < NTILES) {
            nB0 = wb[(t + 1) * 128 + lane];
            nB1 = wb[(t + 1) * 128 + 64 + lane];
        }
        f32x4 acc = {0.f, 0.f, 0.f, 0.f};
        acc = __builtin_amdgcn_mfma_f32_16x16x32_bf16(A0, B0, acc, 0, 0, 0);
        acc = __builtin_amdgcn_mfma_f32_16x16x32_bf16(A1, B1, acc, 0, 0, 0);
#pragma unroll
        for (int i = 0; i < 4; ++i) {
            if (i < rmax)
                outp[(size_t)i * NCOL + t * 16] = __float2bfloat16(acc[i]);
        }
        B0 = nB0; B1 = nB1;
    }
}

// ------------- fused segment-max + root + bias (+relu): 4 edges / wave-iter -------------
// Quarter q = lane>>4 handles edge i+q, sublane j = lane&15 handles channels
// 4j..4j+3 (8 B gathers); 2-deep software pipeline (records prefetched 2 ahead,
// corner loads issued 1 iter ahead). Duplicates at the tail are free under max.
__global__ __launch_bounds__(256) void agg_node(
    const int4* __restrict__ sorted, const unsigned int* __restrict__ cursor,
    const __hip_bfloat16* __restrict__ XK, const float* __restrict__ bias,
    float* __restrict__ out, int N, int do_relu)
{
    const int lane = threadIdx.x & 63;
    const int n = blockIdx.x * 4 + (threadIdx.x >> 6);
    if (n >= N) return;
    const int q = lane >> 4, j = lane & 15;
    const int beg = (n > 0) ? (int)cursor[n - 1] : 0;
    const int end = (int)cursor[n];

    float m0 = -INFINITY, m1 = -INFINITY, m2 = -INFINITY, m3 = -INFINITY;
    if (beg < end) {
        const int last = end - 1;
        int4 rA = sorted[min(beg + q, last)];
        int4 rB = sorted[min(beg + 4 + q, last)];
        const char* baseA = (const char*)XK + (size_t)(unsigned)rA.x * ROWB + (j << 3);
        uint2 g0 = *(const uint2*)(baseA + (((unsigned)rA.y & 31) << 7));
        uint2 g1 = *(const uint2*)(baseA + ((((unsigned)rA.y >> 5) & 31) << 7));
        uint2 g2 = *(const uint2*)(baseA + ((((unsigned)rA.y >> 10) & 31) << 7));
        uint2 g3 = *(const uint2*)(baseA + ((((unsigned)rA.y >> 15) & 31) << 7));
        for (int i = beg; i < end; i += 4) {
            int4 rC = sorted[min(i + 8 + q, last)];
            const char* baseB = (const char*)XK + (size_t)(unsigned)rB.x * ROWB + (j << 3);
            uint2 h0 = *(const uint2*)(baseB + (((unsigned)rB.y & 31) << 7));
            uint2 h1 = *(const uint2*)(baseB + ((((unsigned)rB.y >> 5) & 31) << 7));
            uint2 h2 = *(const uint2*)(baseB + ((((unsigned)rB.y >> 10) & 31) << 7));
            uint2 h3 = *(const uint2*)(baseB + ((((unsigned)rB.y >> 15) & 31) << 7));
            const float f0 = __int_as_float(rA.z);
            const float f1 = __int_as_float(rA.w);
            const float w00 = (1.f - f0) * (1.f - f1);
            const float w10 = f0 * (1.f - f1);
            const float w01 = (1.f - f0) * f1;
            const float w11 = f0 * f1;
            float v0 = fmaf(blo(g3.x), w11, fmaf(blo(g2.x), w01, fmaf(blo(g1.x), w10, blo(g0.x) * w00)));
            float v1 = fmaf(bhi(g3.x), w11, fmaf(bhi(g2.x), w01, fmaf(bhi(g1.x), w10, bhi(g0.x) * w00)));
            float v2 = fmaf(blo(g3.y), w11, fmaf(blo(g2.y), w01, fmaf(blo(g1.y), w10, blo(g0.y) * w00)));
            float v3 = fmaf(bhi(g3.y), w11, fmaf(bhi(g2.y), w01, fmaf(bhi(g1.y), w10, bhi(g0.y) * w00)));
            m0 = fmaxf(m0, v0); m1 = fmaxf(m1, v1);
            m2 = fmaxf(m2, v2); m3 = fmaxf(m3, v3);
            rA = rB; rB = rC;
            g0 = h0; g1 = h1; g2 = h2; g3 = h3;
        }
    }
    m0 = fmaxf(m0, __shfl_xor(m0, 16, 64)); m0 = fmaxf(m0, __shfl_xor(m0, 32, 64));
    m1 = fmaxf(m1, __shfl_xor(m1, 16, 64)); m1 = fmaxf(m1, __shfl_xor(m1, 32, 64));
    m2 = fmaxf(m2, __shfl_xor(m2, 16, 64)); m2 = fmaxf(m2, __shfl_xor(m2, 32, 64));
    m3 = fmaxf(m3, __shfl_xor(m3, 16, 64)); m3 = fmaxf(m3, __shfl_xor(m3, 32, 64));
    const float a0 = isfinite(m0) ? m0 : 0.f;
    const float a1 = isfinite(m1) ? m1 : 0.f;
    const float a2 = isfinite(m2) ? m2 : 0.f;
    const float a3 = isfinite(m3) ? m3 : 0.f;

    const uint2 rt = *(const uint2*)((const char*)XK + (size_t)(unsigned)n * ROWB
                                     + KK * 128 + (j << 3));
    const float4 bv = *(const float4*)(bias + 4 * j);
    float r0 = a0 + blo(rt.x) + bv.x;
    float r1 = a1 + bhi(rt.x) + bv.y;
    float r2 = a2 + blo(rt.y) + bv.z;
    float r3 = a3 + bhi(rt.y) + bv.w;
    if (do_relu) {
        r0 = fmaxf(r0, 0.f); r1 = fmaxf(r1, 0.f);
        r2 = fmaxf(r2, 0.f); r3 = fmaxf(r3, 0.f);
    }
    if (q == 0)
        *(float4*)(out + (size_t)n * CHANNELS + 4 * j) = make_float4(r0, r1, r2, r3);
}

extern "C" void kernel_launch(void* const* d_in, const int* in_sizes, int n_in,
                              void* d_out, int out_size, void* d_ws, size_t ws_size,
                              hipStream_t stream) {
    const float* x     = (const float*)d_in[0];
    const int*   ei    = (const int*)d_in[1];
    const float* ps    = (const float*)d_in[2];
    const float* W1    = (const float*)d_in[3];
    const float* root1 = (const float*)d_in[4];
    const float* bias1 = (const float*)d_in[5];
    const float* W2    = (const float*)d_in[6];
    const float* root2 = (const float*)d_in[7];
    const float* bias2 = (const float*)d_in[8];
    float* out = (float*)d_out;

    const int N = in_sizes[0] / CHANNELS;
    const int E = in_sizes[1] / 2;

    // ---- workspace layout (~205 MB) ----
    char* ws = (char*)d_ws;
    __hip_bfloat16* xk = (__hip_bfloat16*)ws;                       // N*1664*2 = 166.4 MB
    size_t off = (size_t)N * NCOL * sizeof(__hip_bfloat16);
    float* h = (float*)(ws + off);                                  // N*64*4 = 12.8 MB
    off += (size_t)N * CHANNELS * sizeof(float);
    int4* sorted = (int4*)(ws + off);                               // E*16 = 25.6 MB
    off += (size_t)E * sizeof(int4);
    const size_t wb_bytes = (size_t)NTILES * 2 * 64 * 8 * 2;        // 212992
    unsigned int* counts = (unsigned int*)(ws + off);               // max(N*4, wb)
    __hip_bfloat16* Wb = (__hip_bfloat16*)counts;                   // aliases counts (dead after scan_c)
    off += ((size_t)N * 4 > wb_bytes ? (size_t)N * 4 : wb_bytes);
    unsigned int* cursor = (unsigned int*)(ws + off);               // N*4
    off += (size_t)N * 4;
    unsigned int* bsum = (unsigned int*)(ws + off);                 // ≤4 KB

    const int prep_blocks = (NTILES * 2 * 64 * 8 + 255) / 256;
    const int gemm_blocks = (N + 63) / 64;
    const int node_blocks = (N + 3) / 4;
    const int edgeT_blocks = (E + 255) / 256;
    const int nT_blocks = (N + 255) / 256;
    const int scan_blocks = (N + 1023) / 1024;

    // ---- CSR prefix (hist + scan), then layer 1 with scatter FUSED into gemm ----
    zero_counts<<<nT_blocks, 256, 0, stream>>>(counts, N);
    hist_dst<<<edgeT_blocks, 256, 0, stream>>>(ei, counts, E);
    scan_a<<<scan_blocks, 256, 0, stream>>>(counts, bsum, N);
    scan_b<<<1, 64, 0, stream>>>(bsum, scan_blocks);
    scan_c<<<scan_blocks, 256, 0, stream>>>(counts, bsum, cursor, N);

    prep_w<<<prep_blocks, 256, 0, stream>>>(W1, root1, Wb);   // clobbers counts (dead)
    gemm_scatter<<<gemm_blocks + edgeT_blocks, 256, 0, stream>>>(
        x, Wb, xk, N, gemm_blocks, ei, ps, cursor, sorted, E);
    agg_node<<<node_blocks, 256, 0, stream>>>(sorted, cursor, xk, bias1, h, N, 1);

    // ---- layer 2: out = spline_conv(h, W2, root2, bias2) ----
    prep_w<<<prep_blocks, 256, 0, stream>>>(W2, root2, Wb);
    gemm_scatter<<<gemm_blocks, 256, 0, stream>>>(
        h, Wb, xk, N, gemm_blocks, ei, ps, cursor, sorted, 0);
    agg_node<<<node_blocks, 256, 0, stream>>>(sorted, cursor, xk, bias2, out, N, 0);
}

// Round 8
// 504.603 us; speedup vs baseline: 1.3427x; 1.1821x over previous
//
#include <hip/hip_runtime.h>
#include <hip/hip_bf16.h>
#include <math.h>

#define CHANNELS 64
#define KK 25                   // 5x5 kernels
#define NBLK 26                 // 25 spline kernels + 1 root block
#define NCOL (NBLK * CHANNELS)  // 1664 columns of the fused GEMM
#define NTILES (NCOL / 16)      // 104 col-tiles of 16
#define ROWB (NCOL * 2)         // 3328 bytes per xk row
#define GROUP_TILES 8
#define GROUP_BYTES (GROUP_TILES * 2048)  // 16 KB per staged group
#define NGROUPS (NTILES / GROUP_TILES)    // 13 (exact)

typedef __attribute__((ext_vector_type(8))) short bf16x8;
typedef __attribute__((ext_vector_type(4))) float f32x4;
typedef unsigned int u32;

// RNE float -> bf16 bits
__device__ __forceinline__ u32 f2bfu(float f) {
    u32 u = __float_as_uint(f);
    return (u + 0x7FFFu + ((u >> 16) & 1u)) >> 16;
}
__device__ __forceinline__ short f2bf(float f) { return (short)f2bfu(f); }
// unpack packed bf16 pair (u32) -> floats
__device__ __forceinline__ float blo(u32 u) { return __uint_as_float(u << 16); }
__device__ __forceinline__ float bhi(u32 u) { return __uint_as_float(u & 0xffff0000u); }

// async global->LDS, 16 B per lane (lds dest = uniform base + lane*16)
__device__ __forceinline__ void async_copy16(const void* g, void* l) {
    __builtin_amdgcn_global_load_lds(
        (const __attribute__((address_space(1))) u32*)g,
        (__attribute__((address_space(3))) u32*)l, 16, 0, 0);
}

// ---------------- CSR build: histogram(+rank) -> parallel scan ----------------

__global__ __launch_bounds__(256) void zero_counts(u32* __restrict__ c, int n) {
    int i = blockIdx.x * 256 + threadIdx.x;
    if (i < n) c[i] = 0u;
}

// rank[e] = arrival order of edge e within its dst bucket (atomic's old value)
__global__ __launch_bounds__(256) void hist_rank(const int* __restrict__ ei,
                                                 u32* __restrict__ counts,
                                                 u32* __restrict__ rank, int E) {
    int e = blockIdx.x * 256 + threadIdx.x;
    if (e < E) rank[e] = atomicAdd(&counts[ei[E + e]], 1u);
}

// A: per-block (1024 items) sums
__global__ __launch_bounds__(256) void scan_a(const u32* __restrict__ counts,
                                              u32* __restrict__ bsum, int N) {
    const int t = threadIdx.x;
    const int base = blockIdx.x * 1024 + t * 4;
    uint4 v = make_uint4(0, 0, 0, 0);
    if (base + 3 < N) v = *(const uint4*)(counts + base);
    else {
        if (base < N)     v.x = counts[base];
        if (base + 1 < N) v.y = counts[base + 1];
        if (base + 2 < N) v.z = counts[base + 2];
    }
    u32 s = v.x + v.y + v.z + v.w;
    for (int off = 32; off; off >>= 1) s += __shfl_down(s, off, 64);
    __shared__ u32 red[4];
    if ((t & 63) == 0) red[t >> 6] = s;
    __syncthreads();
    if (t == 0) bsum[blockIdx.x] = red[0] + red[1] + red[2] + red[3];
}

// B: single-wave exclusive scan of bsum[nb]
__global__ __launch_bounds__(64) void scan_b(u32* __restrict__ bsum, int nb) {
    const int lane = threadIdx.x;
    u32 run = 0;
    for (int base = 0; base < nb; base += 64) {
        u32 v = (base + lane < nb) ? bsum[base + lane] : 0u;
        const u32 orig = v;
        for (int off = 1; off < 64; off <<= 1) {
            u32 u = __shfl_up(v, off, 64);
            if (lane >= off) v += u;
        }
        if (base + lane < nb) bsum[base + lane] = run + v - orig;
        run += __shfl(v, 63, 64);
    }
}

// C: exclusive prefix -> cursor[0..N-1]; also cursor[N] = total (=E)
__global__ __launch_bounds__(256) void scan_c(const u32* __restrict__ counts,
                                              const u32* __restrict__ bsum,
                                              u32* __restrict__ cursor, int N) {
    const int t = threadIdx.x;
    const int base = blockIdx.x * 1024 + t * 4;
    uint4 v = make_uint4(0, 0, 0, 0);
    if (base + 3 < N) v = *(const uint4*)(counts + base);
    else {
        if (base < N)     v.x = counts[base];
        if (base + 1 < N) v.y = counts[base + 1];
        if (base + 2 < N) v.z = counts[base + 2];
    }
    __shared__ u32 ps[256];
    ps[t] = v.x + v.y + v.z + v.w;
    __syncthreads();
    for (int off = 1; off < 256; off <<= 1) {
        u32 u = (t >= off) ? ps[t - off] : 0u;
        __syncthreads();
        ps[t] += u;
        __syncthreads();
    }
    u32 ex = ((t > 0) ? ps[t - 1] : 0u) + bsum[blockIdx.x];
    if (base < N)     cursor[base]     = ex;
    if (base + 1 < N) cursor[base + 1] = ex + v.x;
    if (base + 2 < N) cursor[base + 2] = ex + v.x + v.y;
    if (base + 3 < N) cursor[base + 3] = ex + v.x + v.y + v.z;
    if (base <= N - 1 && N - 1 <= base + 3)   // this thread covers the last node
        cursor[N] = ex + v.x + v.y + v.z + v.w;
}

// ---------------- fused xk GEMM (LDS-staged MFMA) + edge scatter ----------------

// Repack [W | root] fp32 -> Wb bf16 in B-fragment order.
__global__ __launch_bounds__(256) void prep_w(const float* __restrict__ W,
                                              const float* __restrict__ root,
                                              __hip_bfloat16* __restrict__ Wb) {
    int idx = blockIdx.x * 256 + threadIdx.x;   // 104*2*64*8 = 106496
    if (idx >= NTILES * 2 * 64 * 8) return;
    int j = idx & 7;
    int l = (idx >> 3) & 63;
    int q = (idx >> 9) & 1;
    int t = idx >> 10;
    int col  = t * 16 + (l & 15);
    int k    = q * 32 + (l >> 4) * 8 + j;
    int kk   = col >> 6;
    int o    = col & 63;
    float src = (kk < KK) ? W[kk * 4096 + k * 64 + o] : root[k * 64 + o];
    ((unsigned short*)Wb)[idx] = (unsigned short)f2bf(src);
}

// Heterogeneous grid: blocks [0, gemm_blocks) compute XK = X @ [W|root] with Wb
// double-buffer staged into LDS via async global_load_lds (canonical §5 pattern);
// blocks >= gemm_blocks scatter 8 B edge records into CSR order WITHOUT atomics
// (pos = exclusive cursor[dst] + precomputed rank[e]).
__global__ __launch_bounds__(256) void gemm_scatter(
    const float* __restrict__ X, const __hip_bfloat16* __restrict__ Wb,
    __hip_bfloat16* __restrict__ XK, int N, int gemm_blocks,
    const int* __restrict__ ei, const float* __restrict__ ps,
    const u32* __restrict__ rank, const u32* __restrict__ cursor,
    uint2* __restrict__ sorted, int E)
{
    __shared__ __align__(16) char lds[2][GROUP_BYTES];

    if ((int)blockIdx.x >= gemm_blocks) {
        // ---- scatter path (no barriers, early return) ----
        int e = ((int)blockIdx.x - gemm_blocks) * 256 + threadIdx.x;
        if (e >= E) return;
        const int src = ei[e];
        const int dst = ei[E + e];
        const float v0 = ps[2 * e]     * 4.0f;
        const float v1 = ps[2 * e + 1] * 4.0f;
        const float fb0 = floorf(v0), fb1 = floorf(v1);
        const float f0 = v0 - fb0, f1 = v1 - fb1;
        const int b0 = max(min((int)fb0, 4), 0);
        const int b1 = max(min((int)fb1, 4), 0);
        const u32 f0q = (u32)(f0 * 65536.0f);
        const u32 f1q = (u32)(f1 * 65536.0f);
        uint2 rec;
        rec.x = (u32)src | ((u32)b0 << 16) | ((u32)b1 << 19);
        rec.y = f0q | (f1q << 16);
        sorted[cursor[dst] + rank[e]] = rec;
        return;
    }

    // ---- gemm path ----
    const int lane = threadIdx.x & 63;
    const int wv   = threadIdx.x >> 6;
    const int rb   = blockIdx.x * 64 + wv * 16;
    const int m    = lane & 15;
    const int quad = lane >> 4;

    const int rowc = min(rb + m, N - 1);
    const float* __restrict__ xp = X + (size_t)rowc * CHANNELS + quad * 8;
    float af[16];
    *(float4*)(af)      = *(const float4*)(xp);
    *(float4*)(af + 4)  = *(const float4*)(xp + 4);
    *(float4*)(af + 8)  = *(const float4*)(xp + 32);
    *(float4*)(af + 12) = *(const float4*)(xp + 36);
    bf16x8 A0, A1;
#pragma unroll
    for (int j = 0; j < 8; ++j) { A0[j] = f2bf(af[j]); A1[j] = f2bf(af[8 + j]); }

    const int r0 = rb + quad * 4;
    __hip_bfloat16* __restrict__ outp = XK + (size_t)r0 * NCOL + m;
    const int rmax = N - r0;

    // stage(g, buf): block cooperatively copies group g (16 KB) into lds[buf].
    // wave wv covers [wv*4096, +4096): 4 async 1 KB wave-copies (16 B/lane).
    const char* __restrict__ wbc = (const char*)Wb;
#define STAGE(g, buf)                                                          \
    {                                                                          \
        const char* gsrc = wbc + (size_t)(g) * GROUP_BYTES + wv * 4096 + lane * 16; \
        char* lbase = lds[buf] + wv * 4096;                                    \
        async_copy16(gsrc,        lbase);                                      \
        async_copy16(gsrc + 1024, lbase + 1024);                               \
        async_copy16(gsrc + 2048, lbase + 2048);                               \
        async_copy16(gsrc + 3072, lbase + 3072);                               \
    }

    STAGE(0, 0)
    for (int g = 0; g < NGROUPS; ++g) {
        __syncthreads();           // drains staged loads for g; prior readers done
        if (g + 1 < NGROUPS) STAGE(g + 1, (g + 1) & 1)
        const char* lb = lds[g & 1] + lane * 16;
#pragma unroll
        for (int tt = 0; tt < GROUP_TILES; ++tt) {
            bf16x8 B0 = *(const bf16x8*)(lb + tt * 2048);
            bf16x8 B1 = *(const bf16x8*)(lb + tt * 2048 + 1024);
            f32x4 acc = {0.f, 0.f, 0.f, 0.f};
            acc = __builtin_amdgcn_mfma_f32_16x16x32_bf16(A0, B0, acc, 0, 0, 0);
            acc = __builtin_amdgcn_mfma_f32_16x16x32_bf16(A1, B1, acc, 0, 0, 0);
            const int t = g * GROUP_TILES + tt;
#pragma unroll
            for (int i = 0; i < 4; ++i) {
                if (i < rmax)
                    outp[(size_t)i * NCOL + t * 16] = __float2bfloat16(acc[i]);
            }
        }
    }
#undef STAGE
}

// ------------- fused segment-max + root + bias (+relu): 4 edges / wave-iter -------------
// Quarter q = lane>>4 handles edge i+q, sublane j = lane&15 handles channels
// 4j..4j+3 (8 B gathers); 2-deep software pipeline. 8 B records:
// x = src | b0<<16 | b1<<19 ; y = f0q16 | f1q16<<16 (fixed point /65536).
__global__ __launch_bounds__(256) void agg_node(
    const uint2* __restrict__ sorted, const u32* __restrict__ cursor,
    const __hip_bfloat16* __restrict__ XK, const float* __restrict__ bias,
    float* __restrict__ out, int N, int do_relu)
{
    const int lane = threadIdx.x & 63;
    const int n = blockIdx.x * 4 + (threadIdx.x >> 6);
    if (n >= N) return;
    const int q = lane >> 4, j = lane & 15;
    const int beg = (int)cursor[n];
    const int end = (int)cursor[n + 1];

    float m0 = -INFINITY, m1 = -INFINITY, m2 = -INFINITY, m3 = -INFINITY;
    if (beg < end) {
        const int last = end - 1;
        uint2 rA = sorted[min(beg + q, last)];
        uint2 rB = sorted[min(beg + 4 + q, last)];
        {
        }
        const char* baseA = (const char*)XK + (size_t)(rA.x & 0xffff) * ROWB + (j << 3);
        int oA = ((int)((rA.x >> 16) & 7) + 5 * (int)((rA.x >> 19) & 7)) << 7;
        uint2 g0 = *(const uint2*)(baseA + oA);
        uint2 g1 = *(const uint2*)(baseA + oA + 128);
        uint2 g2 = *(const uint2*)(baseA + oA + 640);
        uint2 g3 = *(const uint2*)(baseA + oA + 768);
        for (int i = beg; i < end; i += 4) {
            uint2 rC = sorted[min(i + 8 + q, last)];
            const char* baseB = (const char*)XK + (size_t)(rB.x & 0xffff) * ROWB + (j << 3);
            int oB = ((int)((rB.x >> 16) & 7) + 5 * (int)((rB.x >> 19) & 7)) << 7;
            uint2 h0 = *(const uint2*)(baseB + oB);
            uint2 h1 = *(const uint2*)(baseB + oB + 128);
            uint2 h2 = *(const uint2*)(baseB + oB + 640);
            uint2 h3 = *(const uint2*)(baseB + oB + 768);
            const float f0 = (float)(rA.y & 0xffff) * (1.0f / 65536.0f);
            const float f1 = (float)(rA.y >> 16)    * (1.0f / 65536.0f);
            const float w00 = (1.f - f0) * (1.f - f1);
            const float w10 = f0 * (1.f - f1);
            const float w01 = (1.f - f0) * f1;
            const float w11 = f0 * f1;
            float v0 = fmaf(blo(g3.x), w11, fmaf(blo(g2.x), w01, fmaf(blo(g1.x), w10, blo(g0.x) * w00)));
            float v1 = fmaf(bhi(g3.x), w11, fmaf(bhi(g2.x), w01, fmaf(bhi(g1.x), w10, bhi(g0.x) * w00)));
            float v2 = fmaf(blo(g3.y), w11, fmaf(blo(g2.y), w01, fmaf(blo(g1.y), w10, blo(g0.y) * w00)));
            float v3 = fmaf(bhi(g3.y), w11, fmaf(bhi(g2.y), w01, fmaf(bhi(g1.y), w10, bhi(g0.y) * w00)));
            m0 = fmaxf(m0, v0); m1 = fmaxf(m1, v1);
            m2 = fmaxf(m2, v2); m3 = fmaxf(m3, v3);
            rA = rB; rB = rC;
            g0 = h0; g1 = h1; g2 = h2; g3 = h3;
        }
    }
    m0 = fmaxf(m0, __shfl_xor(m0, 16, 64)); m0 = fmaxf(m0, __shfl_xor(m0, 32, 64));
    m1 = fmaxf(m1, __shfl_xor(m1, 16, 64)); m1 = fmaxf(m1, __shfl_xor(m1, 32, 64));
    m2 = fmaxf(m2, __shfl_xor(m2, 16, 64)); m2 = fmaxf(m2, __shfl_xor(m2, 32, 64));
    m3 = fmaxf(m3, __shfl_xor(m3, 16, 64)); m3 = fmaxf(m3, __shfl_xor(m3, 32, 64));
    const float a0 = isfinite(m0) ? m0 : 0.f;
    const float a1 = isfinite(m1) ? m1 : 0.f;
    const float a2 = isfinite(m2) ? m2 : 0.f;
    const float a3 = isfinite(m3) ? m3 : 0.f;

    const uint2 rt = *(const uint2*)((const char*)XK + (size_t)(unsigned)n * ROWB
                                     + KK * 128 + (j << 3));
    const float4 bv = *(const float4*)(bias + 4 * j);
    float r0 = a0 + blo(rt.x) + bv.x;
    float r1 = a1 + bhi(rt.x) + bv.y;
    float r2 = a2 + blo(rt.y) + bv.z;
    float r3 = a3 + bhi(rt.y) + bv.w;
    if (do_relu) {
        r0 = fmaxf(r0, 0.f); r1 = fmaxf(r1, 0.f);
        r2 = fmaxf(r2, 0.f); r3 = fmaxf(r3, 0.f);
    }
    if (q == 0)
        *(float4*)(out + (size_t)n * CHANNELS + 4 * j) = make_float4(r0, r1, r2, r3);
}

extern "C" void kernel_launch(void* const* d_in, const int* in_sizes, int n_in,
                              void* d_out, int out_size, void* d_ws, size_t ws_size,
                              hipStream_t stream) {
    const float* x     = (const float*)d_in[0];
    const int*   ei    = (const int*)d_in[1];
    const float* ps    = (const float*)d_in[2];
    const float* W1    = (const float*)d_in[3];
    const float* root1 = (const float*)d_in[4];
    const float* bias1 = (const float*)d_in[5];
    const float* W2    = (const float*)d_in[6];
    const float* root2 = (const float*)d_in[7];
    const float* bias2 = (const float*)d_in[8];
    float* out = (float*)d_out;

    const int N = in_sizes[0] / CHANNELS;
    const int E = in_sizes[1] / 2;

    // ---- workspace layout (~199 MB) ----
    char* ws = (char*)d_ws;
    __hip_bfloat16* xk = (__hip_bfloat16*)ws;                       // N*1664*2 = 166.4 MB
    size_t off = (size_t)N * NCOL * sizeof(__hip_bfloat16);
    float* h = (float*)(ws + off);                                  // 12.8 MB
    off += (size_t)N * CHANNELS * sizeof(float);
    uint2* sorted = (uint2*)(ws + off);                             // E*8 = 12.8 MB
    off += (size_t)E * sizeof(uint2);
    u32* rank = (u32*)(ws + off);                                   // E*4 = 6.4 MB
    off += (size_t)E * sizeof(u32);
    const size_t wb_bytes = (size_t)NTILES * 2 * 64 * 8 * 2;        // 212992
    u32* counts = (u32*)(ws + off);                                 // max(N*4, wb)
    __hip_bfloat16* Wb = (__hip_bfloat16*)counts;                   // aliases counts (dead after scan_c)
    off += ((size_t)N * 4 > wb_bytes ? (size_t)N * 4 : wb_bytes);
    u32* cursor = (u32*)(ws + off);                                 // (N+1)*4
    off += ((size_t)N + 1) * 4;
    u32* bsum = (u32*)(ws + off);                                   // ≤4 KB

    const int prep_blocks = (NTILES * 2 * 64 * 8 + 255) / 256;
    const int gemm_blocks = (N + 63) / 64;
    const int node_blocks = (N + 3) / 4;
    const int edgeT_blocks = (E + 255) / 256;
    const int nT_blocks = (N + 255) / 256;
    const int scan_blocks = (N + 1023) / 1024;

    // ---- CSR prefix: hist (with rank capture) + scan ----
    zero_counts<<<nT_blocks, 256, 0, stream>>>(counts, N);
    hist_rank<<<edgeT_blocks, 256, 0, stream>>>(ei, counts, rank, E);
    scan_a<<<scan_blocks, 256, 0, stream>>>(counts, bsum, N);
    scan_b<<<1, 64, 0, stream>>>(bsum, scan_blocks);
    scan_c<<<scan_blocks, 256, 0, stream>>>(counts, bsum, cursor, N);

    // ---- layer 1 (scatter fused into gemm as hetero grid) ----
    prep_w<<<prep_blocks, 256, 0, stream>>>(W1, root1, Wb);   // clobbers counts (dead)
    gemm_scatter<<<gemm_blocks + edgeT_blocks, 256, 0, stream>>>(
        x, Wb, xk, N, gemm_blocks, ei, ps, rank, cursor, sorted, E);
    agg_node<<<node_blocks, 256, 0, stream>>>(sorted, cursor, xk, bias1, h, N, 1);

    // ---- layer 2 ----
    prep_w<<<prep_blocks, 256, 0, stream>>>(W2, root2, Wb);
    gemm_scatter<<<gemm_blocks, 256, 0, stream>>>(
        h, Wb, xk, N, gemm_blocks, ei, ps, rank, cursor, sorted, 0);
    agg_node<<<node_blocks, 256, 0, stream>>>(sorted, cursor, xk, bias2, out, N, 0);
}